// Round 1
// baseline (2128.495 us; speedup 1.0000x reference)
//
#include <hip/hip_runtime.h>

// BipartiteGNN: 3-layer bipartite SAGEConv + global mean pool + linear.
// NS=NT=100000, E=1.6M per direction, F=H=64, fp32.
//
// Strategy:
//  - CSR build (counting sort by dst) once per launch for each edge direction.
//  - Per conv: h1 = x_src @ Wl^T (dense GEMM), out = x_dst @ Wr^T + b (GEMM),
//    then out[i] += inv_deg[i] * sum_{j in N(i)} h1[j]  (wave-per-node gather).
//  - Scratch: d_ws holds B0,B1 + pooled; unused edge_attr inputs hold
//    temp/CSR/metadata and B2,B3 (harness restores inputs before every launch,
//    and every scratch value is fully rewritten before read -> idempotent).

#define FDIM 64

// ---------------- CSR build ----------------

__global__ void hist_kernel(const int* __restrict__ dst, int* __restrict__ cnt, int E) {
  int e = blockIdx.x * 256 + threadIdx.x;
  if (e < E) atomicAdd(&cnt[dst[e]], 1);
}

__global__ void scan_kernel(const int* __restrict__ cnt, int* __restrict__ off,
                            int* __restrict__ cursor, float* __restrict__ inv_deg, int N) {
  __shared__ int part[256];
  int t = threadIdx.x;
  int C = (N + 255) / 256;
  int lo = t * C, hi = min(N, lo + C);
  int s = 0;
  for (int i = lo; i < hi; ++i) s += cnt[i];
  part[t] = s;
  __syncthreads();
  for (int d = 1; d < 256; d <<= 1) {
    int v = 0;
    if (t >= d) v = part[t - d];
    __syncthreads();
    part[t] += v;
    __syncthreads();
  }
  int run = (t > 0) ? part[t - 1] : 0;
  for (int i = lo; i < hi; ++i) {
    off[i] = run;
    cursor[i] = run;
    int c = cnt[i];
    inv_deg[i] = 1.0f / (float)max(c, 1);
    run += c;
  }
  if (t == 255) off[N] = run;
}

__global__ void scatter_kernel(const int* __restrict__ src, const int* __restrict__ dst,
                               int* __restrict__ cursor, int* __restrict__ csr, int E) {
  int e = blockIdx.x * 256 + threadIdx.x;
  if (e < E) {
    int p = atomicAdd(&cursor[dst[e]], 1);
    csr[p] = src[e];
  }
}

// ---------------- dense GEMM: Y[n][h] = sum_k X[n][k]*W[h][k] (+ bias[h]) ----------------

__global__ __launch_bounds__(256) void gemm64_kernel(const float* __restrict__ X,
                                                     const float* __restrict__ W,
                                                     const float* __restrict__ bias,
                                                     float* __restrict__ Y, int N) {
  __shared__ __align__(16) float xsh[64][65];
  __shared__ __align__(16) float wt[64][68];  // wt[k][h] = W[h][k], padded
  int t = threadIdx.x;
  for (int i = t; i < 4096; i += 256) {
    int h = i >> 6, k = i & 63;
    wt[k][h] = W[i];
  }
  int n0 = blockIdx.x * 64;
  const float4* Xv = (const float4*)X;
  for (int i = t; i < 1024; i += 256) {
    int n = i >> 4, k4 = i & 15;
    float4 v = make_float4(0.f, 0.f, 0.f, 0.f);
    if (n0 + n < N) v = Xv[(size_t)(n0 + n) * 16 + k4];
    xsh[n][k4 * 4 + 0] = v.x;
    xsh[n][k4 * 4 + 1] = v.y;
    xsh[n][k4 * 4 + 2] = v.z;
    xsh[n][k4 * 4 + 3] = v.w;
  }
  __syncthreads();
  int ng = t >> 4;           // 16 node groups of 4 rows
  int h0 = (t & 15) * 4;     // 4 output features per thread
  float b0 = 0.f, b1 = 0.f, b2 = 0.f, b3 = 0.f;
  if (bias) { b0 = bias[h0]; b1 = bias[h0 + 1]; b2 = bias[h0 + 2]; b3 = bias[h0 + 3]; }
  float acc[4][4];
#pragma unroll
  for (int j = 0; j < 4; ++j) { acc[j][0] = b0; acc[j][1] = b1; acc[j][2] = b2; acc[j][3] = b3; }
#pragma unroll
  for (int k = 0; k < 64; ++k) {
    float4 w = *(const float4*)&wt[k][h0];
#pragma unroll
    for (int j = 0; j < 4; ++j) {
      float x = xsh[ng * 4 + j][k];
      acc[j][0] += x * w.x;
      acc[j][1] += x * w.y;
      acc[j][2] += x * w.z;
      acc[j][3] += x * w.w;
    }
  }
  float4* Yv = (float4*)Y;
#pragma unroll
  for (int j = 0; j < 4; ++j) {
    int n = n0 + ng * 4 + j;
    if (n < N)
      Yv[(size_t)n * 16 + (h0 >> 2)] = make_float4(acc[j][0], acc[j][1], acc[j][2], acc[j][3]);
  }
}

// ---------------- aggregation: Y[i] += inv_deg[i] * sum_{j in CSR(i)} Msg[j] ----------------

__global__ __launch_bounds__(256) void agg_kernel(const float* __restrict__ Msg,
                                                  const int* __restrict__ off,
                                                  const int* __restrict__ csr,
                                                  const float* __restrict__ inv_deg,
                                                  float* __restrict__ Y, int N) {
  int w = (blockIdx.x * 256 + threadIdx.x) >> 6;  // one wave per dst node
  int lane = threadIdx.x & 63;
  if (w >= N) return;
  int s0 = off[w], s1 = off[w + 1];
  float acc = 0.f;
  for (int base = s0; base < s1; base += 64) {
    int idx = base + lane;
    int mysrc = (idx < s1) ? csr[idx] : 0;
    int m = min(64, s1 - base);
    int j = 0;
    for (; j + 3 < m; j += 4) {
      int sA = __shfl(mysrc, j, 64);
      int sB = __shfl(mysrc, j + 1, 64);
      int sC = __shfl(mysrc, j + 2, 64);
      int sD = __shfl(mysrc, j + 3, 64);
      float a = Msg[(size_t)sA * 64 + lane];
      float b = Msg[(size_t)sB * 64 + lane];
      float c = Msg[(size_t)sC * 64 + lane];
      float d = Msg[(size_t)sD * 64 + lane];
      acc += (a + b) + (c + d);
    }
    for (; j < m; ++j) {
      int s = __shfl(mysrc, j, 64);
      acc += Msg[(size_t)s * 64 + lane];
    }
  }
  Y[(size_t)w * 64 + lane] += inv_deg[w] * acc;
}

// ---------------- pooling + final linear ----------------

__global__ __launch_bounds__(256) void pool_kernel(const float* __restrict__ xs,
                                                   const float* __restrict__ xt,
                                                   float* __restrict__ pooled, int N) {
  int t = threadIdx.x;
  int f = t & 63;
  int rg = t >> 6;  // 4 row groups
  float acc = 0.f;
  int total = 2 * N;
  for (int r = blockIdx.x * 4 + rg; r < total; r += gridDim.x * 4) {
    const float* p = (r < N) ? (xs + (size_t)r * 64) : (xt + (size_t)(r - N) * 64);
    acc += p[f];
  }
  __shared__ float red[256];
  red[t] = acc;
  __syncthreads();
  if (t < 128) red[t] += red[t + 128];
  __syncthreads();
  if (t < 64) {
    float v = red[t] + red[t + 64];
    atomicAdd(&pooled[t], v);
  }
}

__global__ void final_kernel(const float* __restrict__ pooled, const float* __restrict__ linW,
                             const float* __restrict__ linb, float* __restrict__ out, float invM) {
  int t = threadIdx.x;  // 64 threads
  float v = pooled[t] * invM * linW[t];
#pragma unroll
  for (int o = 32; o > 0; o >>= 1) v += __shfl_down(v, o, 64);
  if (t == 0) out[0] = v + linb[0];
}

// ---------------- launch ----------------

extern "C" void kernel_launch(void* const* d_in, const int* in_sizes, int n_in,
                              void* d_out, int out_size, void* d_ws, size_t ws_size,
                              hipStream_t stream) {
  const float* x_source = (const float*)d_in[0];
  const float* x_target = (const float*)d_in[1];
  float* scratchA = (float*)d_in[2];  // edge_attr_s2t: 12.8M floats, unused input
  float* scratchB = (float*)d_in[3];  // edge_attr_t2s: 12.8M floats, unused input
  const float* W_l_s2t = (const float*)d_in[4];
  const float* b_s2t   = (const float*)d_in[5];
  const float* W_r_s2t = (const float*)d_in[6];
  const float* W_l_t2s = (const float*)d_in[7];
  const float* b_t2s   = (const float*)d_in[8];
  const float* W_r_t2s = (const float*)d_in[9];
  const float* lin_W   = (const float*)d_in[10];
  const float* lin_b   = (const float*)d_in[11];
  const int* ei_s2t    = (const int*)d_in[12];
  const int* ei_t2s    = (const int*)d_in[13];

  const int NS = in_sizes[0] / FDIM;
  const int NT = in_sizes[1] / FDIM;
  const int E  = in_sizes[12] / 2;
  const int L  = in_sizes[4] / (FDIM * FDIM);
  const size_t NF = (size_t)NS * FDIM;  // NS==NT==100000 here

  // scratchA layout (elements):
  float* temp     = scratchA;                 // NF
  int*   csr_t    = (int*)(scratchA + NF);    // E
  int*   csr_s    = csr_t + E;                // E
  float* inv_t    = (float*)(csr_s + E);      // NS
  float* inv_s    = inv_t + NS;               // NS
  int*   off_t    = (int*)(inv_s + NS);       // NS+1
  int*   off_s    = off_t + NS + 1;           // NS+1
  int*   cnt      = off_s + NS + 1;           // NS
  int*   cursor   = cnt + NS;                 // NS
  // scratchB layout:
  float* B2 = scratchB;       // NF
  float* B3 = scratchB + NF;  // NF
  // d_ws layout:
  float* B0 = (float*)d_ws;          // NF
  float* B1 = B0 + NF;               // NF
  float* pooled = B1 + NF;           // 64

  const int* src_s2t = ei_s2t;
  const int* dst_s2t = ei_s2t + E;
  const int* src_t2s = ei_t2s;
  const int* dst_t2s = ei_t2s + E;

  int gE = (E + 255) / 256;

  // --- CSR build, s2t (dst in target space) ---
  hipMemsetAsync(cnt, 0, (size_t)NT * 4, stream);
  hist_kernel<<<gE, 256, 0, stream>>>(dst_s2t, cnt, E);
  scan_kernel<<<1, 256, 0, stream>>>(cnt, off_t, cursor, inv_t, NT);
  scatter_kernel<<<gE, 256, 0, stream>>>(src_s2t, dst_s2t, cursor, csr_t, E);

  // --- CSR build, t2s (dst in source space) ---
  hipMemsetAsync(cnt, 0, (size_t)NS * 4, stream);
  hist_kernel<<<gE, 256, 0, stream>>>(dst_t2s, cnt, E);
  scan_kernel<<<1, 256, 0, stream>>>(cnt, off_s, cursor, inv_s, NS);
  scatter_kernel<<<gE, 256, 0, stream>>>(src_t2s, dst_t2s, cursor, csr_s, E);

  const float* xs_cur = x_source;
  const float* xt_cur = x_target;
  int gS = (NS + 63) / 64;
  int gT = (NT + 63) / 64;
  int aS = (NS * 64 + 255) / 256;
  int aT = (NT * 64 + 255) / 256;

  for (int l = 0; l < L; ++l) {
    float* nxs;
    float* nxt;
    if ((l & 1) == 0) { nxs = B0; nxt = B1; }
    else              { nxs = B2; nxt = B3; }
    const float* Wl1 = W_l_s2t + (size_t)l * 4096;
    const float* Wr1 = W_r_s2t + (size_t)l * 4096;
    const float* bb1 = b_s2t + (size_t)l * 64;
    const float* Wl2 = W_l_t2s + (size_t)l * 4096;
    const float* Wr2 = W_r_t2s + (size_t)l * 4096;
    const float* bb2 = b_t2s + (size_t)l * 64;

    // conv s2t -> new xt
    gemm64_kernel<<<gS, 256, 0, stream>>>(xs_cur, Wl1, nullptr, temp, NS);
    gemm64_kernel<<<gT, 256, 0, stream>>>(xt_cur, Wr1, bb1, nxt, NT);
    agg_kernel<<<aT, 256, 0, stream>>>(temp, off_t, csr_t, inv_t, nxt, NT);

    // conv t2s -> new xs
    gemm64_kernel<<<gT, 256, 0, stream>>>(xt_cur, Wl2, nullptr, temp, NT);
    gemm64_kernel<<<gS, 256, 0, stream>>>(xs_cur, Wr2, bb2, nxs, NS);
    agg_kernel<<<aS, 256, 0, stream>>>(temp, off_s, csr_s, inv_s, nxs, NS);

    xs_cur = nxs;
    xt_cur = nxt;
  }

  // pooling + final
  hipMemsetAsync(pooled, 0, 64 * 4, stream);
  pool_kernel<<<1024, 256, 0, stream>>>(xs_cur, xt_cur, pooled, NS);
  final_kernel<<<1, 64, 0, stream>>>(pooled, lin_W, lin_b, (float*)d_out,
                                     1.0f / (float)(NS + NT));
}

// Round 2
// 1580.266 us; speedup vs baseline: 1.3469x; 1.3469x over previous
//
#include <hip/hip_runtime.h>

// BipartiteGNN: 3-layer bipartite SAGEConv + global mean pool + linear.
// NS=NT=100000, E=1.6M per direction, F=H=64, fp32.
//
// R2: replaced serial single-block scan (2x288us, latency-bound, 0.05% occ)
// with 3-phase multi-block scan (blocksum -> scan of block sums -> write).

#define FDIM 64

// ---------------- CSR build ----------------

__global__ void hist_kernel(const int* __restrict__ dst, int* __restrict__ cnt, int E) {
  int e = blockIdx.x * 256 + threadIdx.x;
  if (e < E) atomicAdd(&cnt[dst[e]], 1);
}

// Phase A: per-block (256-elem) sums of cnt
__global__ __launch_bounds__(256) void blocksum_kernel(const int* __restrict__ cnt,
                                                       int* __restrict__ bsum, int N) {
  __shared__ int sh[256];
  int t = threadIdx.x;
  int i = blockIdx.x * 256 + t;
  sh[t] = (i < N) ? cnt[i] : 0;
  __syncthreads();
  for (int d = 128; d > 0; d >>= 1) {
    if (t < d) sh[t] += sh[t + d];
    __syncthreads();
  }
  if (t == 0) bsum[blockIdx.x] = sh[0];
}

// Phase B: exclusive scan of bsum in-place (nb <= 512), one block of 256
__global__ __launch_bounds__(256) void scanb_kernel(int* __restrict__ bsum, int nb) {
  __shared__ int sh[512];
  int t = threadIdx.x;
  sh[t] = (t < nb) ? bsum[t] : 0;
  sh[t + 256] = (t + 256 < nb) ? bsum[t + 256] : 0;
  __syncthreads();
  // Hillis-Steele inclusive over 512 entries, 2 per thread
  for (int d = 1; d < 512; d <<= 1) {
    int v0 = (t >= d) ? sh[t - d] : 0;
    int v1 = (t + 256 >= d) ? sh[t + 256 - d] : 0;
    __syncthreads();
    sh[t] += v0;
    sh[t + 256] += v1;
    __syncthreads();
  }
  if (t < nb) bsum[t] = (t > 0) ? sh[t - 1] : 0;
  if (t + 256 < nb) bsum[t + 256] = sh[t + 255];
}

// Phase C: write off/cursor/inv_deg using block prefix + intra-block scan
__global__ __launch_bounds__(256) void scanc_kernel(const int* __restrict__ cnt,
                                                    const int* __restrict__ bsum_ex,
                                                    int* __restrict__ off, int* __restrict__ cursor,
                                                    float* __restrict__ inv_deg, int N) {
  __shared__ int sh[256];
  int t = threadIdx.x;
  int i = blockIdx.x * 256 + t;
  int c = (i < N) ? cnt[i] : 0;
  sh[t] = c;
  __syncthreads();
  for (int d = 1; d < 256; d <<= 1) {
    int v = (t >= d) ? sh[t - d] : 0;
    __syncthreads();
    sh[t] += v;
    __syncthreads();
  }
  int excl = bsum_ex[blockIdx.x] + sh[t] - c;
  if (i < N) {
    off[i] = excl;
    cursor[i] = excl;
    inv_deg[i] = 1.0f / (float)max(c, 1);
    if (i == N - 1) off[N] = excl + c;
  }
}

__global__ void scatter_kernel(const int* __restrict__ src, const int* __restrict__ dst,
                               int* __restrict__ cursor, int* __restrict__ csr, int E) {
  int e = blockIdx.x * 256 + threadIdx.x;
  if (e < E) {
    int p = atomicAdd(&cursor[dst[e]], 1);
    csr[p] = src[e];
  }
}

// ---------------- dense GEMM: Y[n][h] = sum_k X[n][k]*W[h][k] (+ bias[h]) ----------------

__global__ __launch_bounds__(256) void gemm64_kernel(const float* __restrict__ X,
                                                     const float* __restrict__ W,
                                                     const float* __restrict__ bias,
                                                     float* __restrict__ Y, int N) {
  __shared__ __align__(16) float xsh[64][65];
  __shared__ __align__(16) float wt[64][68];  // wt[k][h] = W[h][k], padded
  int t = threadIdx.x;
  for (int i = t; i < 4096; i += 256) {
    int h = i >> 6, k = i & 63;
    wt[k][h] = W[i];
  }
  int n0 = blockIdx.x * 64;
  const float4* Xv = (const float4*)X;
  for (int i = t; i < 1024; i += 256) {
    int n = i >> 4, k4 = i & 15;
    float4 v = make_float4(0.f, 0.f, 0.f, 0.f);
    if (n0 + n < N) v = Xv[(size_t)(n0 + n) * 16 + k4];
    xsh[n][k4 * 4 + 0] = v.x;
    xsh[n][k4 * 4 + 1] = v.y;
    xsh[n][k4 * 4 + 2] = v.z;
    xsh[n][k4 * 4 + 3] = v.w;
  }
  __syncthreads();
  int ng = t >> 4;           // 16 node groups of 4 rows
  int h0 = (t & 15) * 4;     // 4 output features per thread
  float b0 = 0.f, b1 = 0.f, b2 = 0.f, b3 = 0.f;
  if (bias) { b0 = bias[h0]; b1 = bias[h0 + 1]; b2 = bias[h0 + 2]; b3 = bias[h0 + 3]; }
  float acc[4][4];
#pragma unroll
  for (int j = 0; j < 4; ++j) { acc[j][0] = b0; acc[j][1] = b1; acc[j][2] = b2; acc[j][3] = b3; }
#pragma unroll
  for (int k = 0; k < 64; ++k) {
    float4 w = *(const float4*)&wt[k][h0];
#pragma unroll
    for (int j = 0; j < 4; ++j) {
      float x = xsh[ng * 4 + j][k];
      acc[j][0] += x * w.x;
      acc[j][1] += x * w.y;
      acc[j][2] += x * w.z;
      acc[j][3] += x * w.w;
    }
  }
  float4* Yv = (float4*)Y;
#pragma unroll
  for (int j = 0; j < 4; ++j) {
    int n = n0 + ng * 4 + j;
    if (n < N)
      Yv[(size_t)n * 16 + (h0 >> 2)] = make_float4(acc[j][0], acc[j][1], acc[j][2], acc[j][3]);
  }
}

// ---------------- aggregation: Y[i] += inv_deg[i] * sum_{j in CSR(i)} Msg[j] ----------------

__global__ __launch_bounds__(256) void agg_kernel(const float* __restrict__ Msg,
                                                  const int* __restrict__ off,
                                                  const int* __restrict__ csr,
                                                  const float* __restrict__ inv_deg,
                                                  float* __restrict__ Y, int N) {
  int w = (blockIdx.x * 256 + threadIdx.x) >> 6;  // one wave per dst node
  int lane = threadIdx.x & 63;
  if (w >= N) return;
  int s0 = off[w], s1 = off[w + 1];
  float acc = 0.f;
  for (int base = s0; base < s1; base += 64) {
    int idx = base + lane;
    int mysrc = (idx < s1) ? csr[idx] : 0;
    int m = min(64, s1 - base);
    int j = 0;
    for (; j + 3 < m; j += 4) {
      int sA = __shfl(mysrc, j, 64);
      int sB = __shfl(mysrc, j + 1, 64);
      int sC = __shfl(mysrc, j + 2, 64);
      int sD = __shfl(mysrc, j + 3, 64);
      float a = Msg[(size_t)sA * 64 + lane];
      float b = Msg[(size_t)sB * 64 + lane];
      float c = Msg[(size_t)sC * 64 + lane];
      float d = Msg[(size_t)sD * 64 + lane];
      acc += (a + b) + (c + d);
    }
    for (; j < m; ++j) {
      int s = __shfl(mysrc, j, 64);
      acc += Msg[(size_t)s * 64 + lane];
    }
  }
  Y[(size_t)w * 64 + lane] += inv_deg[w] * acc;
}

// ---------------- pooling + final linear ----------------

__global__ __launch_bounds__(256) void pool_kernel(const float* __restrict__ xs,
                                                   const float* __restrict__ xt,
                                                   float* __restrict__ pooled, int N) {
  int t = threadIdx.x;
  int f = t & 63;
  int rg = t >> 6;  // 4 row groups
  float acc = 0.f;
  int total = 2 * N;
  for (int r = blockIdx.x * 4 + rg; r < total; r += gridDim.x * 4) {
    const float* p = (r < N) ? (xs + (size_t)r * 64) : (xt + (size_t)(r - N) * 64);
    acc += p[f];
  }
  __shared__ float red[256];
  red[t] = acc;
  __syncthreads();
  if (t < 128) red[t] += red[t + 128];
  __syncthreads();
  if (t < 64) {
    float v = red[t] + red[t + 64];
    atomicAdd(&pooled[t], v);
  }
}

__global__ void final_kernel(const float* __restrict__ pooled, const float* __restrict__ linW,
                             const float* __restrict__ linb, float* __restrict__ out, float invM) {
  int t = threadIdx.x;  // 64 threads
  float v = pooled[t] * invM * linW[t];
#pragma unroll
  for (int o = 32; o > 0; o >>= 1) v += __shfl_down(v, o, 64);
  if (t == 0) out[0] = v + linb[0];
}

// ---------------- launch ----------------

extern "C" void kernel_launch(void* const* d_in, const int* in_sizes, int n_in,
                              void* d_out, int out_size, void* d_ws, size_t ws_size,
                              hipStream_t stream) {
  const float* x_source = (const float*)d_in[0];
  const float* x_target = (const float*)d_in[1];
  float* scratchA = (float*)d_in[2];  // edge_attr_s2t: 12.8M floats, unused input
  float* scratchB = (float*)d_in[3];  // edge_attr_t2s: 12.8M floats, unused input
  const float* W_l_s2t = (const float*)d_in[4];
  const float* b_s2t   = (const float*)d_in[5];
  const float* W_r_s2t = (const float*)d_in[6];
  const float* W_l_t2s = (const float*)d_in[7];
  const float* b_t2s   = (const float*)d_in[8];
  const float* W_r_t2s = (const float*)d_in[9];
  const float* lin_W   = (const float*)d_in[10];
  const float* lin_b   = (const float*)d_in[11];
  const int* ei_s2t    = (const int*)d_in[12];
  const int* ei_t2s    = (const int*)d_in[13];

  const int NS = in_sizes[0] / FDIM;
  const int NT = in_sizes[1] / FDIM;
  const int E  = in_sizes[12] / 2;
  const int L  = in_sizes[4] / (FDIM * FDIM);
  const size_t NF = (size_t)NS * FDIM;  // NS==NT==100000 here

  // scratchA layout (elements):
  float* temp     = scratchA;                 // NF
  int*   csr_t    = (int*)(scratchA + NF);    // E
  int*   csr_s    = csr_t + E;                // E
  float* inv_t    = (float*)(csr_s + E);      // NS
  float* inv_s    = inv_t + NS;               // NS
  int*   off_t    = (int*)(inv_s + NS);       // NS+1
  int*   off_s    = off_t + NS + 1;           // NS+1
  int*   cnt      = off_s + NS + 1;           // NS
  int*   cursor   = cnt + NS;                 // NS
  int*   bsum     = cursor + NS;              // <=512
  // scratchB layout:
  float* B2 = scratchB;       // NF
  float* B3 = scratchB + NF;  // NF
  // d_ws layout:
  float* B0 = (float*)d_ws;          // NF
  float* B1 = B0 + NF;               // NF
  float* pooled = B1 + NF;           // 64

  const int* src_s2t = ei_s2t;
  const int* dst_s2t = ei_s2t + E;
  const int* src_t2s = ei_t2s;
  const int* dst_t2s = ei_t2s + E;

  int gE = (E + 255) / 256;
  int nbT = (NT + 255) / 256;
  int nbS = (NS + 255) / 256;

  // --- CSR build, s2t (dst in target space) ---
  hipMemsetAsync(cnt, 0, (size_t)NT * 4, stream);
  hist_kernel<<<gE, 256, 0, stream>>>(dst_s2t, cnt, E);
  blocksum_kernel<<<nbT, 256, 0, stream>>>(cnt, bsum, NT);
  scanb_kernel<<<1, 256, 0, stream>>>(bsum, nbT);
  scanc_kernel<<<nbT, 256, 0, stream>>>(cnt, bsum, off_t, cursor, inv_t, NT);
  scatter_kernel<<<gE, 256, 0, stream>>>(src_s2t, dst_s2t, cursor, csr_t, E);

  // --- CSR build, t2s (dst in source space) ---
  hipMemsetAsync(cnt, 0, (size_t)NS * 4, stream);
  hist_kernel<<<gE, 256, 0, stream>>>(dst_t2s, cnt, E);
  blocksum_kernel<<<nbS, 256, 0, stream>>>(cnt, bsum, NS);
  scanb_kernel<<<1, 256, 0, stream>>>(bsum, nbS);
  scanc_kernel<<<nbS, 256, 0, stream>>>(cnt, bsum, off_s, cursor, inv_s, NS);
  scatter_kernel<<<gE, 256, 0, stream>>>(src_t2s, dst_t2s, cursor, csr_s, E);

  const float* xs_cur = x_source;
  const float* xt_cur = x_target;
  int gS = (NS + 63) / 64;
  int gT = (NT + 63) / 64;
  int aS = (NS * 64 + 255) / 256;
  int aT = (NT * 64 + 255) / 256;

  for (int l = 0; l < L; ++l) {
    float* nxs;
    float* nxt;
    if ((l & 1) == 0) { nxs = B0; nxt = B1; }
    else              { nxs = B2; nxt = B3; }
    const float* Wl1 = W_l_s2t + (size_t)l * 4096;
    const float* Wr1 = W_r_s2t + (size_t)l * 4096;
    const float* bb1 = b_s2t + (size_t)l * 64;
    const float* Wl2 = W_l_t2s + (size_t)l * 4096;
    const float* Wr2 = W_r_t2s + (size_t)l * 4096;
    const float* bb2 = b_t2s + (size_t)l * 64;

    // conv s2t -> new xt
    gemm64_kernel<<<gS, 256, 0, stream>>>(xs_cur, Wl1, nullptr, temp, NS);
    gemm64_kernel<<<gT, 256, 0, stream>>>(xt_cur, Wr1, bb1, nxt, NT);
    agg_kernel<<<aT, 256, 0, stream>>>(temp, off_t, csr_t, inv_t, nxt, NT);

    // conv t2s -> new xs
    gemm64_kernel<<<gT, 256, 0, stream>>>(xt_cur, Wl2, nullptr, temp, NT);
    gemm64_kernel<<<gS, 256, 0, stream>>>(xs_cur, Wr2, bb2, nxs, NS);
    agg_kernel<<<aS, 256, 0, stream>>>(temp, off_s, csr_s, inv_s, nxs, NS);

    xs_cur = nxs;
    xt_cur = nxt;
  }

  // pooling + final
  hipMemsetAsync(pooled, 0, 64 * 4, stream);
  pool_kernel<<<1024, 256, 0, stream>>>(xs_cur, xt_cur, pooled, NS);
  final_kernel<<<1, 64, 0, stream>>>(pooled, lin_W, lin_b, (float*)d_out,
                                     1.0f / (float)(NS + NT));
}